// Round 1
// baseline (284.350 us; speedup 1.0000x reference)
//
#include <hip/hip_runtime.h>
#include <hip/hip_bf16.h>

#define NB 8192
#define ND 128
#define NTILE 64   // 8192 / 128

static constexpr float F_ALPHA  = 2.0f;
static constexpr float F_BETA   = 50.0f;
static constexpr float F_BASE   = 0.5f;
static constexpr float F_MARGIN = 0.1f;

typedef __attribute__((ext_vector_type(8))) short short8;
typedef __attribute__((ext_vector_type(4))) float f32x4;

// monotone float<->uint encoding for atomic min/max
__device__ __forceinline__ unsigned fenc(float f) {
  unsigned u = __float_as_uint(f);
  return (u & 0x80000000u) ? ~u : (u | 0x80000000u);
}
__device__ __forceinline__ float fdec(unsigned k) {
  unsigned u = (k & 0x80000000u) ? (k & 0x7FFFFFFFu) : ~k;
  return __uint_as_float(u);
}

__device__ __forceinline__ void async16(const void* g, void* l) {
  __builtin_amdgcn_global_load_lds(
      (const __attribute__((address_space(1))) void*)g,
      (__attribute__((address_space(3))) void*)l, 16, 0, 0);
}

__global__ void k_convert(const float4* __restrict__ in, ushort4* __restrict__ out) {
  int i = blockIdx.x * 256 + threadIdx.x;
  float4 v = in[i];
  __hip_bfloat16 a = __float2bfloat16(v.x), b = __float2bfloat16(v.y),
                 c = __float2bfloat16(v.z), d = __float2bfloat16(v.w);
  ushort4 o;
  o.x = *(unsigned short*)&a; o.y = *(unsigned short*)&b;
  o.z = *(unsigned short*)&c; o.w = *(unsigned short*)&d;
  out[i] = o;
}

// One 128x128 sim tile per block; 4 waves in 2x2, each wave 64x64 via 4x4
// fragments of mfma_f32_16x16x32_bf16 over K=128 (4 k-steps).
// PASS 0: per-row pos_min / neg_max extrema (atomic min/max, encoded).
// PASS 1: hard-masked exp sums (atomicAdd per row).
template<int PASS>
__global__ __launch_bounds__(256, 2)
void k_simpass(const __hip_bfloat16* __restrict__ E,
               const int* __restrict__ lab,
               unsigned* __restrict__ pmKey,
               unsigned* __restrict__ nmKey,
               float* __restrict__ pSum,
               float* __restrict__ nSum)
{
  __shared__ __align__(16) __hip_bfloat16 sA[128 * 128];
  __shared__ __align__(16) __hip_bfloat16 sB[128 * 128];
  __shared__ int   sLr[128], sLc[128];
  __shared__ float sPMn[128], sNMx[128];

  const int t    = threadIdx.x;
  const int lane = t & 63, wid = t >> 6;
  const int wRow = wid >> 1, wCol = wid & 1;
  const int q    = lane >> 4, r15 = lane & 15;
  const int rowBase = blockIdx.y * 128;
  const int colBase = blockIdx.x * 128;

  if (t < 128) {
    sLr[t] = lab[rowBase + t];
    if (PASS == 1) sPMn[t] = fdec(pmKey[rowBase + t]);
  } else {
    int rr = t - 128;
    sLc[rr] = lab[colBase + rr];
    if (PASS == 1) sNMx[rr] = fdec(nmKey[rowBase + rr]);
  }

  // Stage A (rows) and B (cols) tiles: 128 rows x 128 k of bf16 = 32 KB each.
  // LDS kept linear for global_load_lds; XOR swizzle applied on the GLOBAL
  // source address (involution), and again on the ds_read side.
  const char* gA = (const char*)E + (size_t)rowBase * 256;
  const char* gB = (const char*)E + (size_t)colBase * 256;
#pragma unroll
  for (int rch = 0; rch < 8; ++rch) {
    int lin = rch * 4096 + wid * 1024 + lane * 16;   // linear LDS byte offset
    int row = lin >> 8;
    int kb  = lin & 255;
    int kbs = kb ^ ((row & 7) << 4);                 // pre-swizzled source col
    char* dstA = (char*)sA + rch * 4096 + wid * 1024; // wave-uniform base
    char* dstB = (char*)sB + rch * 4096 + wid * 1024;
    async16(gA + (size_t)row * 256 + kbs, dstA);
    async16(gB + (size_t)row * 256 + kbs, dstB);
  }
  __syncthreads();

  f32x4 acc[4][4];
#pragma unroll
  for (int mi = 0; mi < 4; ++mi)
#pragma unroll
    for (int ni = 0; ni < 4; ++ni)
      acc[mi][ni] = (f32x4){0.f, 0.f, 0.f, 0.f};

#pragma unroll
  for (int kk = 0; kk < 4; ++kk) {
    const int kbyte = kk * 64 + q * 16;  // lane's 8 bf16 along K
    short8 afr[4], bfr[4];
#pragma unroll
    for (int mi = 0; mi < 4; ++mi) {
      int ar = wRow * 64 + mi * 16 + r15;
      afr[mi] = *(const short8*)((const char*)sA + ar * 256 + (kbyte ^ ((ar & 7) << 4)));
    }
#pragma unroll
    for (int ni = 0; ni < 4; ++ni) {
      int bc = wCol * 64 + ni * 16 + r15;
      bfr[ni] = *(const short8*)((const char*)sB + bc * 256 + (kbyte ^ ((bc & 7) << 4)));
    }
#pragma unroll
    for (int mi = 0; mi < 4; ++mi)
#pragma unroll
      for (int ni = 0; ni < 4; ++ni)
        acc[mi][ni] = __builtin_amdgcn_mfma_f32_16x16x32_bf16(
            afr[mi], bfr[ni], acc[mi][ni], 0, 0, 0);
  }

  // ---- epilogue ----
  // C layout (m89-verified): col = lane&15, row = (lane>>4)*4 + reg
  int cl[4], cg[4];
#pragma unroll
  for (int ni = 0; ni < 4; ++ni) {
    int ct = wCol * 64 + ni * 16 + r15;
    cl[ni] = sLc[ct];
    cg[ni] = colBase + ct;
  }

#pragma unroll
  for (int mi = 0; mi < 4; ++mi) {
#pragma unroll
    for (int rg = 0; rg < 4; ++rg) {
      const int rT = wRow * 64 + mi * 16 + q * 4 + rg;
      const int rG = rowBase + rT;
      const int lr = sLr[rT];
      if (PASS == 0) {
        float mn = __builtin_inff(), mx = -__builtin_inff();
#pragma unroll
        for (int ni = 0; ni < 4; ++ni) {
          float s = acc[mi][ni][rg];
          if (lr == cl[ni]) {
            if (rG != cg[ni]) mn = fminf(mn, s);
          } else {
            mx = fmaxf(mx, s);
          }
        }
#pragma unroll
        for (int d = 1; d < 16; d <<= 1) {
          mn = fminf(mn, __shfl_xor(mn, d));
          mx = fmaxf(mx, __shfl_xor(mx, d));
        }
        if (r15 == 0) {
          if (mn < __builtin_inff())  atomicMin(&pmKey[rG], fenc(mn));
          if (mx > -__builtin_inff()) atomicMax(&nmKey[rG], fenc(mx));
        }
      } else {
        const float pm = sPMn[rT];
        const float nm = sNMx[rT];
        float ps = 0.f, ns = 0.f;
#pragma unroll
        for (int ni = 0; ni < 4; ++ni) {
          float s = acc[mi][ni][rg];
          if (lr == cl[ni]) {
            // hard positive: pos pair & (sim - MARGIN < neg_max)
            if (rG != cg[ni] && (s - F_MARGIN < nm))
              ps += __expf(-F_ALPHA * (s - F_BASE));
          } else {
            // hard negative: neg pair & (sim + MARGIN > pos_min)
            if (s + F_MARGIN > pm)
              ns += __expf(F_BETA * (s - F_BASE));
          }
        }
#pragma unroll
        for (int d = 1; d < 16; d <<= 1) {
          ps += __shfl_xor(ps, d);
          ns += __shfl_xor(ns, d);
        }
        if (r15 == 0) {
          if (ps > 0.f) atomicAdd(&pSum[rG], ps);
          if (ns > 0.f) atomicAdd(&nSum[rG], ns);
        }
      }
    }
  }
}

__global__ void k_final(const unsigned* __restrict__ pmKey,
                        const unsigned* __restrict__ nmKey,
                        const float* __restrict__ pSum,
                        const float* __restrict__ nSum,
                        float* __restrict__ out)
{
  const int t = threadIdx.x;
  float ls = 0.f, cnt = 0.f;
  for (int r = t; r < NB; r += 256) {
    unsigned pk = pmKey[r], nk = nmKey[r];
    bool pe = pk < 0xFF800000u;   // < enc(+inf): some positive pair existed
    bool ne = nk > 0x007FFFFFu;   // > enc(-inf): some negative pair existed
    if (pe && ne) {
      float pm = fdec(pk), nm = fdec(nk);
      // hard_pos.any <=> hard_neg.any <=> pos_min - MARGIN < neg_max
      if (pm - F_MARGIN < nm) {
        ls += log1pf(pSum[r]) / F_ALPHA + log1pf(nSum[r]) / F_BETA;
        cnt += 1.f;
      }
    }
  }
#pragma unroll
  for (int d = 1; d < 64; d <<= 1) {
    ls  += __shfl_xor(ls, d);
    cnt += __shfl_xor(cnt, d);
  }
  __shared__ float sL[4], sC[4];
  if ((t & 63) == 0) { sL[t >> 6] = ls; sC[t >> 6] = cnt; }
  __syncthreads();
  if (t == 0) {
    float a = sL[0] + sL[1] + sL[2] + sL[3];
    float c = sC[0] + sC[1] + sC[2] + sC[3];
    out[0] = a / fmaxf(c, 1.f);
  }
}

extern "C" void kernel_launch(void* const* d_in, const int* in_sizes, int n_in,
                              void* d_out, int out_size, void* d_ws, size_t ws_size,
                              hipStream_t stream)
{
  const float* emb = (const float*)d_in[0];
  const int*   lab = (const int*)d_in[1];
  float* out = (float*)d_out;

  char* ws = (char*)d_ws;
  __hip_bfloat16* ebf = (__hip_bfloat16*)ws;                    // 2 MB
  unsigned* pmKey = (unsigned*)(ws + 2097152);                  // 32 KB
  unsigned* nmKey = (unsigned*)(ws + 2097152 + 32768);          // 32 KB
  float*    pSum  = (float*)(ws + 2097152 + 65536);             // 32 KB
  float*    nSum  = (float*)(ws + 2097152 + 98304);             // 32 KB

  // identities: pos_min -> +max key (0xFF..), neg_max -> 0, sums -> 0
  hipMemsetAsync(pmKey, 0xFF, 32768, stream);
  hipMemsetAsync(nmKey, 0x00, 32768, stream);
  hipMemsetAsync(pSum,  0x00, 65536, stream);  // pSum + nSum contiguous

  k_convert<<<NB * ND / (256 * 4), 256, 0, stream>>>((const float4*)emb, (ushort4*)ebf);

  dim3 grid(NTILE, NTILE);
  k_simpass<0><<<grid, 256, 0, stream>>>(ebf, lab, pmKey, nmKey, pSum, nSum);
  k_simpass<1><<<grid, 256, 0, stream>>>(ebf, lab, pmKey, nmKey, pSum, nSum);
  k_final<<<1, 256, 0, stream>>>(pmKey, nmKey, pSum, nSum, out);
}

// Round 2
// 124.844 us; speedup vs baseline: 2.2776x; 2.2776x over previous
//
#include <hip/hip_runtime.h>
#include <hip/hip_bf16.h>

#define NB 8192
#define ND 128

static constexpr float F_ALPHA  = 2.0f;
static constexpr float F_BETA   = 50.0f;
static constexpr float F_BASE   = 0.5f;
static constexpr float F_MARGIN = 0.1f;

typedef __attribute__((ext_vector_type(8))) short short8;
typedef __attribute__((ext_vector_type(4))) float f32x4;

// monotone float<->uint encoding for atomic min/max
__device__ __forceinline__ unsigned fenc(float f) {
  unsigned u = __float_as_uint(f);
  return (u & 0x80000000u) ? ~u : (u | 0x80000000u);
}
__device__ __forceinline__ float fdec(unsigned k) {
  unsigned u = (k & 0x80000000u) ? (k & 0x7FFFFFFFu) : ~k;
  return __uint_as_float(u);
}

__device__ __forceinline__ void async16(const void* g, void* l) {
  __builtin_amdgcn_global_load_lds(
      (const __attribute__((address_space(1))) void*)g,
      (__attribute__((address_space(3))) void*)l, 16, 0, 0);
}

__global__ void k_convert(const float4* __restrict__ in, ushort4* __restrict__ out) {
  int i = blockIdx.x * 256 + threadIdx.x;
  float4 v = in[i];
  __hip_bfloat16 a = __float2bfloat16(v.x), b = __float2bfloat16(v.y),
                 c = __float2bfloat16(v.z), d = __float2bfloat16(v.w);
  ushort4 o;
  o.x = *(unsigned short*)&a; o.y = *(unsigned short*)&b;
  o.z = *(unsigned short*)&c; o.w = *(unsigned short*)&d;
  out[i] = o;
}

// Block = 128 rows x 1024 cols (8 col-tiles of 128, looped). A-tile resident,
// B-tile single-buffered. Per-row stats accumulated in REGISTERS across the
// col loop; one shuffle+LDS reduce + few global atomics at the end.
// PASS 0: pos_min / neg_max extrema. PASS 1: hard-masked exp sums.
template<int PASS>
__global__ __launch_bounds__(256, 2)
void k_simpass(const __hip_bfloat16* __restrict__ E,
               const int* __restrict__ lab,
               unsigned* __restrict__ pmKey,
               unsigned* __restrict__ nmKey,
               float* __restrict__ pSum,
               float* __restrict__ nSum)
{
  __shared__ __align__(16) __hip_bfloat16 sA[128 * 128];
  __shared__ __align__(16) __hip_bfloat16 sB[128 * 128];
  __shared__ int      sLr[128], sLc[128];
  __shared__ float    sPMn[128], sNMx[128];   // pass 1 inputs
  __shared__ unsigned sMnU[128], sMxU[128];   // pass 0 block-combine
  __shared__ float    sPs[128], sNs[128];     // pass 1 block-combine

  const int t    = threadIdx.x;
  const int lane = t & 63, wid = t >> 6;
  const int wRow = wid >> 1, wCol = wid & 1;
  const int q    = lane >> 4, r15 = lane & 15;
  const int rowBase  = blockIdx.y * 128;
  const int colBase0 = blockIdx.x * 1024;

  if (t < 128) {
    sLr[t] = lab[rowBase + t];
    if (PASS == 0) {
      sMnU[t] = 0xFFFFFFFFu;
      sMxU[t] = 0u;
    } else {
      sPMn[t] = fdec(pmKey[rowBase + t]);
      sNMx[t] = fdec(nmKey[rowBase + t]);
      sPs[t]  = 0.f;
      sNs[t]  = 0.f;
    }
  }

  // Stage A tile once: 128 rows x 128 k bf16 = 32 KB, linear LDS dest,
  // XOR swizzle applied on the global source (involution) and on ds_read.
  const char* gA = (const char*)E + (size_t)rowBase * 256;
#pragma unroll
  for (int rch = 0; rch < 8; ++rch) {
    int lin = rch * 4096 + wid * 1024 + lane * 16;
    int row = lin >> 8;
    int kb  = lin & 255;
    int kbs = kb ^ ((row & 7) << 4);
    async16(gA + (size_t)row * 256 + kbs, (char*)sA + rch * 4096 + wid * 1024);
  }
  __syncthreads();   // A staged, prologue LDS writes visible

  // Hoist per-lane row data to registers (broadcast LDS reads, conflict-free)
  int   lrr[4][4];
  float pmr[4][4], nmr[4][4];
#pragma unroll
  for (int mi = 0; mi < 4; ++mi)
#pragma unroll
    for (int rg = 0; rg < 4; ++rg) {
      const int rT = wRow * 64 + mi * 16 + q * 4 + rg;
      lrr[mi][rg] = sLr[rT];
      if (PASS == 1) { pmr[mi][rg] = sPMn[rT]; nmr[mi][rg] = sNMx[rT]; }
    }

  // register accumulators across the column loop
  float st1[4][4], st2[4][4];  // pass0: {min,max}; pass1: {psum,nsum}
#pragma unroll
  for (int mi = 0; mi < 4; ++mi)
#pragma unroll
    for (int rg = 0; rg < 4; ++rg) {
      st1[mi][rg] = (PASS == 0) ?  __builtin_inff() : 0.f;
      st2[mi][rg] = (PASS == 0) ? -__builtin_inff() : 0.f;
    }

  for (int ct = 0; ct < 8; ++ct) {
    const int colBase = colBase0 + ct * 128;
    __syncthreads();   // everyone done reading sB/sLc from previous iter

    const char* gB = (const char*)E + (size_t)colBase * 256;
#pragma unroll
    for (int rch = 0; rch < 8; ++rch) {
      int lin = rch * 4096 + wid * 1024 + lane * 16;
      int row = lin >> 8;
      int kb  = lin & 255;
      int kbs = kb ^ ((row & 7) << 4);
      async16(gB + (size_t)row * 256 + kbs, (char*)sB + rch * 4096 + wid * 1024);
    }
    if (t < 128) sLc[t] = lab[colBase + t];
    __syncthreads();   // B tile + col labels ready

    f32x4 acc[4][4];
#pragma unroll
    for (int mi = 0; mi < 4; ++mi)
#pragma unroll
      for (int ni = 0; ni < 4; ++ni)
        acc[mi][ni] = (f32x4){0.f, 0.f, 0.f, 0.f};

#pragma unroll
    for (int kk = 0; kk < 4; ++kk) {
      const int kbyte = kk * 64 + q * 16;
      short8 afr[4], bfr[4];
#pragma unroll
      for (int mi = 0; mi < 4; ++mi) {
        int ar = wRow * 64 + mi * 16 + r15;
        afr[mi] = *(const short8*)((const char*)sA + ar * 256 + (kbyte ^ ((ar & 7) << 4)));
      }
#pragma unroll
      for (int ni = 0; ni < 4; ++ni) {
        int bc = wCol * 64 + ni * 16 + r15;
        bfr[ni] = *(const short8*)((const char*)sB + bc * 256 + (kbyte ^ ((bc & 7) << 4)));
      }
#pragma unroll
      for (int mi = 0; mi < 4; ++mi)
#pragma unroll
        for (int ni = 0; ni < 4; ++ni)
          acc[mi][ni] = __builtin_amdgcn_mfma_f32_16x16x32_bf16(
              afr[mi], bfr[ni], acc[mi][ni], 0, 0, 0);
    }

    // fold this col-tile into register stats
    int cl[4], cg[4];
#pragma unroll
    for (int ni = 0; ni < 4; ++ni) {
      int cT = wCol * 64 + ni * 16 + r15;
      cl[ni] = sLc[cT];
      cg[ni] = colBase + cT;
    }
#pragma unroll
    for (int mi = 0; mi < 4; ++mi) {
#pragma unroll
      for (int rg = 0; rg < 4; ++rg) {
        const int rG = rowBase + wRow * 64 + mi * 16 + q * 4 + rg;
        const int lr = lrr[mi][rg];
#pragma unroll
        for (int ni = 0; ni < 4; ++ni) {
          float s = acc[mi][ni][rg];
          if (PASS == 0) {
            if (lr == cl[ni]) {
              if (rG != cg[ni]) st1[mi][rg] = fminf(st1[mi][rg], s);
            } else {
              st2[mi][rg] = fmaxf(st2[mi][rg], s);
            }
          } else {
            if (lr == cl[ni]) {
              if (rG != cg[ni] && (s - F_MARGIN < nmr[mi][rg]))
                st1[mi][rg] += __expf(-F_ALPHA * (s - F_BASE));
            } else {
              if (s + F_MARGIN > pmr[mi][rg])
                st2[mi][rg] += __expf(F_BETA * (s - F_BASE));
            }
          }
        }
      }
    }
  }

  // ---- block epilogue: 16-lane shuffle reduce -> LDS combine -> global ----
#pragma unroll
  for (int mi = 0; mi < 4; ++mi) {
#pragma unroll
    for (int rg = 0; rg < 4; ++rg) {
      const int rT = wRow * 64 + mi * 16 + q * 4 + rg;
      float v1 = st1[mi][rg], v2 = st2[mi][rg];
      if (PASS == 0) {
#pragma unroll
        for (int d = 1; d < 16; d <<= 1) {
          v1 = fminf(v1, __shfl_xor(v1, d));
          v2 = fmaxf(v2, __shfl_xor(v2, d));
        }
        if (r15 == 0) {
          atomicMin(&sMnU[rT], fenc(v1));
          atomicMax(&sMxU[rT], fenc(v2));
        }
      } else {
#pragma unroll
        for (int d = 1; d < 16; d <<= 1) {
          v1 += __shfl_xor(v1, d);
          v2 += __shfl_xor(v2, d);
        }
        if (r15 == 0) {
          atomicAdd(&sPs[rT], v1);
          atomicAdd(&sNs[rT], v2);
        }
      }
    }
  }
  __syncthreads();
  if (t < 128) {
    if (PASS == 0) {
      atomicMin(&pmKey[rowBase + t], sMnU[t]);
      atomicMax(&nmKey[rowBase + t], sMxU[t]);
    } else {
      atomicAdd(&pSum[rowBase + t], sPs[t]);
      atomicAdd(&nSum[rowBase + t], sNs[t]);
    }
  }
}

__global__ void k_final(const unsigned* __restrict__ pmKey,
                        const unsigned* __restrict__ nmKey,
                        const float* __restrict__ pSum,
                        const float* __restrict__ nSum,
                        float* __restrict__ out)
{
  const int t = threadIdx.x;
  float ls = 0.f, cnt = 0.f;
  for (int r = t; r < NB; r += 256) {
    unsigned pk = pmKey[r], nk = nmKey[r];
    bool pe = pk < 0xFF800000u;   // < enc(+inf): some positive pair existed
    bool ne = nk > 0x007FFFFFu;   // > enc(-inf): some negative pair existed
    if (pe && ne) {
      float pm = fdec(pk), nm = fdec(nk);
      // hard_pos.any <=> hard_neg.any <=> pos_min - MARGIN < neg_max
      if (pm - F_MARGIN < nm) {
        ls += log1pf(pSum[r]) / F_ALPHA + log1pf(nSum[r]) / F_BETA;
        cnt += 1.f;
      }
    }
  }
#pragma unroll
  for (int d = 1; d < 64; d <<= 1) {
    ls  += __shfl_xor(ls, d);
    cnt += __shfl_xor(cnt, d);
  }
  __shared__ float sL[4], sC[4];
  if ((t & 63) == 0) { sL[t >> 6] = ls; sC[t >> 6] = cnt; }
  __syncthreads();
  if (t == 0) {
    float a = sL[0] + sL[1] + sL[2] + sL[3];
    float c = sC[0] + sC[1] + sC[2] + sC[3];
    out[0] = a / fmaxf(c, 1.f);
  }
}

extern "C" void kernel_launch(void* const* d_in, const int* in_sizes, int n_in,
                              void* d_out, int out_size, void* d_ws, size_t ws_size,
                              hipStream_t stream)
{
  const float* emb = (const float*)d_in[0];
  const int*   lab = (const int*)d_in[1];
  float* out = (float*)d_out;

  char* ws = (char*)d_ws;
  __hip_bfloat16* ebf = (__hip_bfloat16*)ws;                    // 2 MB
  unsigned* pmKey = (unsigned*)(ws + 2097152);                  // 32 KB
  unsigned* nmKey = (unsigned*)(ws + 2097152 + 32768);          // 32 KB
  float*    pSum  = (float*)(ws + 2097152 + 65536);             // 32 KB
  float*    nSum  = (float*)(ws + 2097152 + 98304);             // 32 KB

  // identities: pos_min -> +max key (0xFF..), neg_max -> 0, sums -> 0
  hipMemsetAsync(pmKey, 0xFF, 32768, stream);
  hipMemsetAsync(nmKey, 0x00, 32768, stream);
  hipMemsetAsync(pSum,  0x00, 65536, stream);  // pSum + nSum contiguous

  k_convert<<<NB * ND / (256 * 4), 256, 0, stream>>>((const float4*)emb, (ushort4*)ebf);

  dim3 grid(8, 64);   // 8 col-chunks x 64 row-tiles = 512 blocks (2/CU)
  k_simpass<0><<<grid, 256, 0, stream>>>(ebf, lab, pmKey, nmKey, pSum, nSum);
  k_simpass<1><<<grid, 256, 0, stream>>>(ebf, lab, pmKey, nmKey, pSum, nSum);
  k_final<<<1, 256, 0, stream>>>(pmKey, nmKey, pSum, nSum, out);
}

// Round 3
// 105.567 us; speedup vs baseline: 2.6936x; 1.1826x over previous
//
#include <hip/hip_runtime.h>
#include <hip/hip_bf16.h>

#define NB 8192
#define ND 128

static constexpr float F_ALPHA  = 2.0f;
static constexpr float F_BETA   = 50.0f;
static constexpr float F_BASE   = 0.5f;
static constexpr float F_MARGIN = 0.1f;
static constexpr float LOG2E    = 1.4426950408889634f;
// exp(-A*(s-B)) = exp2(s*C1P + C0P); exp(B*(s-B)) = exp2(s*C1N + C0N)
static constexpr float C1P = -F_ALPHA * LOG2E, C0P =  F_ALPHA * F_BASE * LOG2E;
static constexpr float C1N =  F_BETA  * LOG2E, C0N = -F_BETA  * F_BASE * LOG2E;

typedef __attribute__((ext_vector_type(8))) short short8;
typedef __attribute__((ext_vector_type(4))) float f32x4;

// monotone float<->uint encoding for atomic min/max
__device__ __forceinline__ unsigned fenc(float f) {
  unsigned u = __float_as_uint(f);
  return (u & 0x80000000u) ? ~u : (u | 0x80000000u);
}
__device__ __forceinline__ float fdec(unsigned k) {
  unsigned u = (k & 0x80000000u) ? (k & 0x7FFFFFFFu) : ~k;
  return __uint_as_float(u);
}

__device__ __forceinline__ void async16(const void* g, void* l) {
  __builtin_amdgcn_global_load_lds(
      (const __attribute__((address_space(1))) void*)g,
      (__attribute__((address_space(3))) void*)l, 16, 0, 0);
}

__global__ void k_convert(const float4* __restrict__ in, ushort4* __restrict__ out,
                          unsigned* __restrict__ pmKey, unsigned* __restrict__ nmKey,
                          float* __restrict__ pSum, float* __restrict__ nSum) {
  int i = blockIdx.x * 256 + threadIdx.x;
  float4 v = in[i];
  __hip_bfloat16 a = __float2bfloat16(v.x), b = __float2bfloat16(v.y),
                 c = __float2bfloat16(v.z), d = __float2bfloat16(v.w);
  ushort4 o;
  o.x = *(unsigned short*)&a; o.y = *(unsigned short*)&b;
  o.z = *(unsigned short*)&c; o.w = *(unsigned short*)&d;
  out[i] = o;
  if (i < NB) {   // fused stat-array init (replaces 3 memsets)
    pmKey[i] = 0xFFFFFFFFu;   // > fenc(+inf): "no pos seen"
    nmKey[i] = 0u;            // < fenc(-inf): "no neg seen"
    pSum[i]  = 0.f;
    nSum[i]  = 0.f;
  }
}

// Block = 128 rows x 1024 cols as 16 col-tiles of 64, double-buffered.
// A-tile fragments hoisted to registers (col-invariant); ONE barrier per
// col-tile; next tile's global_load_lds issued before current compute.
// PASS 0: pos_min / neg_max extrema. PASS 1: hard-masked exp sums.
template<int PASS>
__global__ __launch_bounds__(256, 2)
void k_simpass(const __hip_bfloat16* __restrict__ E,
               const int* __restrict__ lab,
               unsigned* __restrict__ pmKey,
               unsigned* __restrict__ nmKey,
               float* __restrict__ pSum,
               float* __restrict__ nSum)
{
  __shared__ __align__(16) __hip_bfloat16 sA[128 * 128];
  __shared__ __align__(16) __hip_bfloat16 sB[2][64 * 128];
  __shared__ int      sLr[128];
  __shared__ unsigned sMnU[128], sMxU[128];   // pass 0 block-combine
  __shared__ float    sPs[128], sNs[128];     // pass 1 block-combine
  __shared__ float    sPMn[128], sNMx[128];   // pass 1 inputs

  const int t    = threadIdx.x;
  const int lane = t & 63, wid = t >> 6;
  const int wRow = wid & 1, wCol = wid >> 1;     // 2x2 waves over 128r x 64c
  const int q    = lane >> 4, r15 = lane & 15;
  const int rowBase  = blockIdx.y * 128;
  const int colBase0 = blockIdx.x * 1024;

  if (t < 128) {
    sLr[t] = lab[rowBase + t];
    if (PASS == 0) {
      sMnU[t] = 0xFFFFFFFFu;
      sMxU[t] = 0u;
    } else {
      sPMn[t] = fdec(pmKey[rowBase + t]);
      sNMx[t] = fdec(nmKey[rowBase + t]);
      sPs[t]  = 0.f;
      sNs[t]  = 0.f;
    }
  }

  // Stage A tile (32 KB) + first B tile (16 KB). Linear LDS dest; XOR
  // swizzle pre-applied on the global source (involution) and on ds_read.
  const char* gA = (const char*)E + (size_t)rowBase * 256;
#pragma unroll
  for (int rch = 0; rch < 8; ++rch) {
    int lin = rch * 4096 + t * 16;
    int row = lin >> 8, kb = lin & 255;
    async16(gA + row * 256 + (kb ^ ((row & 7) << 4)),
            (char*)sA + rch * 4096 + wid * 1024);
  }
  {
    const char* gB = (const char*)E + (size_t)colBase0 * 256;
#pragma unroll
    for (int ch = 0; ch < 4; ++ch) {
      int lin = ch * 4096 + t * 16;
      int row = lin >> 8, kb = lin & 255;
      async16(gB + row * 256 + (kb ^ ((row & 7) << 4)),
              (char*)&sB[0][0] + ch * 4096 + wid * 1024);
    }
  }
  __syncthreads();

  // Hoist A fragments: col-tile invariant. 16 x short8 = 64 VGPR.
  short8 afr[4][4];
#pragma unroll
  for (int kk = 0; kk < 4; ++kk)
#pragma unroll
    for (int mi = 0; mi < 4; ++mi) {
      int ar = wRow * 64 + mi * 16 + r15;
      afr[kk][mi] = *(const short8*)((const char*)sA + ar * 256 +
                      ((kk * 64 + q * 16) ^ ((ar & 7) << 4)));
    }

  // Hoist per-row data (C-layout rows: q*4+rg within each 16-row fragment)
  int lrr[16]; float pmr[16], nmr[16];
#pragma unroll
  for (int mi = 0; mi < 4; ++mi)
#pragma unroll
    for (int rg = 0; rg < 4; ++rg) {
      int rT = wRow * 64 + mi * 16 + q * 4 + rg;
      lrr[mi * 4 + rg] = sLr[rT];
      if (PASS == 1) { pmr[mi * 4 + rg] = sPMn[rT]; nmr[mi * 4 + rg] = sNMx[rT]; }
    }

  float st1[16], st2[16];
#pragma unroll
  for (int i = 0; i < 16; ++i) {
    st1[i] = (PASS == 0) ?  __builtin_inff() : 0.f;
    st2[i] = (PASS == 0) ? -__builtin_inff() : 0.f;
  }

  for (int ct = 0; ct < 16; ++ct) {
    const int buf = ct & 1;
    const int colBase = colBase0 + ct * 64;

    // issue next tile's staging FIRST (hides L2 latency under compute)
    if (ct < 15) {
      const char* gB = (const char*)E + (size_t)(colBase + 64) * 256;
#pragma unroll
      for (int ch = 0; ch < 4; ++ch) {
        int lin = ch * 4096 + t * 16;
        int row = lin >> 8, kb = lin & 255;
        async16(gB + row * 256 + (kb ^ ((row & 7) << 4)),
                (char*)&sB[buf ^ 1][0] + ch * 4096 + wid * 1024);
      }
    }

    const int c0 = wCol * 32 + r15;
    int cl[2], cg[2];
    cl[0] = lab[colBase + c0];      cg[0] = colBase + c0;
    cl[1] = lab[colBase + c0 + 16]; cg[1] = colBase + c0 + 16;

    f32x4 acc[4][2];
#pragma unroll
    for (int mi = 0; mi < 4; ++mi) {
      acc[mi][0] = (f32x4){0.f, 0.f, 0.f, 0.f};
      acc[mi][1] = (f32x4){0.f, 0.f, 0.f, 0.f};
    }

#pragma unroll
    for (int kk = 0; kk < 4; ++kk) {
      short8 bfr[2];
#pragma unroll
      for (int ni = 0; ni < 2; ++ni) {
        int bc = wCol * 32 + ni * 16 + r15;
        bfr[ni] = *(const short8*)((const char*)&sB[buf][0] + bc * 256 +
                    ((kk * 64 + q * 16) ^ ((bc & 7) << 4)));
      }
#pragma unroll
      for (int mi = 0; mi < 4; ++mi) {
        acc[mi][0] = __builtin_amdgcn_mfma_f32_16x16x32_bf16(afr[kk][mi], bfr[0], acc[mi][0], 0, 0, 0);
        acc[mi][1] = __builtin_amdgcn_mfma_f32_16x16x32_bf16(afr[kk][mi], bfr[1], acc[mi][1], 0, 0, 0);
      }
    }

    // branchless fold into register stats
#pragma unroll
    for (int mi = 0; mi < 4; ++mi) {
#pragma unroll
      for (int rg = 0; rg < 4; ++rg) {
        const int idx = mi * 4 + rg;
        const int rG  = rowBase + wRow * 64 + mi * 16 + q * 4 + rg;
        const int lr  = lrr[idx];
#pragma unroll
        for (int ni = 0; ni < 2; ++ni) {
          float s = acc[mi][ni][rg];
          bool sameC = (lr == cl[ni]);
          if (PASS == 0) {
            bool isP = sameC && (rG != cg[ni]);
            st1[idx] = fminf(st1[idx], isP   ? s :  __builtin_inff());
            st2[idx] = fmaxf(st2[idx], sameC ? -__builtin_inff() : s);
          } else {
            float arg = sameC ? fmaf(s, C1P, C0P) : fmaf(s, C1N, C0N);
            float e   = __builtin_amdgcn_exp2f(arg);
            bool hp = sameC && (rG != cg[ni]) && (s - F_MARGIN < nmr[idx]);
            bool hn = !sameC && (s + F_MARGIN > pmr[idx]);
            st1[idx] += hp ? e : 0.f;
            st2[idx] += hn ? e : 0.f;
          }
        }
      }
    }
    __syncthreads();   // drains vmcnt(0): next buffer staged; all reads done
  }

  // ---- epilogue: 16-lane shuffle reduce -> LDS combine -> global ----
#pragma unroll
  for (int mi = 0; mi < 4; ++mi) {
#pragma unroll
    for (int rg = 0; rg < 4; ++rg) {
      const int idx = mi * 4 + rg;
      const int rT  = wRow * 64 + mi * 16 + q * 4 + rg;
      float v1 = st1[idx], v2 = st2[idx];
      if (PASS == 0) {
#pragma unroll
        for (int d = 1; d < 16; d <<= 1) {
          v1 = fminf(v1, __shfl_xor(v1, d));
          v2 = fmaxf(v2, __shfl_xor(v2, d));
        }
        if (r15 == 0) {
          atomicMin(&sMnU[rT], fenc(v1));
          atomicMax(&sMxU[rT], fenc(v2));
        }
      } else {
#pragma unroll
        for (int d = 1; d < 16; d <<= 1) {
          v1 += __shfl_xor(v1, d);
          v2 += __shfl_xor(v2, d);
        }
        if (r15 == 0) {
          atomicAdd(&sPs[rT], v1);
          atomicAdd(&sNs[rT], v2);
        }
      }
    }
  }
  __syncthreads();
  if (t < 128) {
    if (PASS == 0) {
      atomicMin(&pmKey[rowBase + t], sMnU[t]);
      atomicMax(&nmKey[rowBase + t], sMxU[t]);
    } else {
      atomicAdd(&pSum[rowBase + t], sPs[t]);
      atomicAdd(&nSum[rowBase + t], sNs[t]);
    }
  }
}

__global__ void k_final(const unsigned* __restrict__ pmKey,
                        const unsigned* __restrict__ nmKey,
                        const float* __restrict__ pSum,
                        const float* __restrict__ nSum,
                        float* __restrict__ out)
{
  const int t = threadIdx.x;
  float ls = 0.f, cnt = 0.f;
  for (int r = t; r < NB; r += 256) {
    unsigned pk = pmKey[r], nk = nmKey[r];
    bool pe = pk < 0xFF800000u;   // < enc(+inf): some positive pair existed
    bool ne = nk > 0x007FFFFFu;   // > enc(-inf): some negative pair existed
    if (pe && ne) {
      float pm = fdec(pk), nm = fdec(nk);
      // hard_pos.any <=> hard_neg.any <=> pos_min - MARGIN < neg_max
      if (pm - F_MARGIN < nm) {
        ls += log1pf(pSum[r]) / F_ALPHA + log1pf(nSum[r]) / F_BETA;
        cnt += 1.f;
      }
    }
  }
#pragma unroll
  for (int d = 1; d < 64; d <<= 1) {
    ls  += __shfl_xor(ls, d);
    cnt += __shfl_xor(cnt, d);
  }
  __shared__ float sL[4], sC[4];
  if ((t & 63) == 0) { sL[t >> 6] = ls; sC[t >> 6] = cnt; }
  __syncthreads();
  if (t == 0) {
    float a = sL[0] + sL[1] + sL[2] + sL[3];
    float c = sC[0] + sC[1] + sC[2] + sC[3];
    out[0] = a / fmaxf(c, 1.f);
  }
}

extern "C" void kernel_launch(void* const* d_in, const int* in_sizes, int n_in,
                              void* d_out, int out_size, void* d_ws, size_t ws_size,
                              hipStream_t stream)
{
  const float* emb = (const float*)d_in[0];
  const int*   lab = (const int*)d_in[1];
  float* out = (float*)d_out;

  char* ws = (char*)d_ws;
  __hip_bfloat16* ebf = (__hip_bfloat16*)ws;                    // 2 MB
  unsigned* pmKey = (unsigned*)(ws + 2097152);                  // 32 KB
  unsigned* nmKey = (unsigned*)(ws + 2097152 + 32768);          // 32 KB
  float*    pSum  = (float*)(ws + 2097152 + 65536);             // 32 KB
  float*    nSum  = (float*)(ws + 2097152 + 98304);             // 32 KB

  k_convert<<<NB * ND / (256 * 4), 256, 0, stream>>>(
      (const float4*)emb, (ushort4*)ebf, pmKey, nmKey, pSum, nSum);

  dim3 grid(8, 64);   // 8 col-chunks x 64 row-tiles = 512 blocks (2/CU)
  k_simpass<0><<<grid, 256, 0, stream>>>(ebf, lab, pmKey, nmKey, pSum, nSum);
  k_simpass<1><<<grid, 256, 0, stream>>>(ebf, lab, pmKey, nmKey, pSum, nSum);
  k_final<<<1, 256, 0, stream>>>(pmKey, nmKey, pSum, nSum, out);
}